// Round 7
// baseline (245.657 us; speedup 1.0000x reference)
//
#include <hip/hip_runtime.h>
#include <hip/hip_bf16.h>
#include <stdint.h>

typedef unsigned short u16;
typedef unsigned int   u32;
typedef short bf16x8 __attribute__((ext_vector_type(8)));
typedef float f32x4  __attribute__((ext_vector_type(4)));
typedef float f32x16 __attribute__((ext_vector_type(16)));

#define MFMA16(A,B,C) __builtin_amdgcn_mfma_f32_16x16x32_bf16((A),(B),(C),0,0,0)
#define MFMA32(A,B,C) __builtin_amdgcn_mfma_f32_32x32x16_bf16((A),(B),(C),0,0,0)

// fp32 -> bf16 round-to-nearest-even
__device__ __forceinline__ u16 f2b(float x) {
  u32 u = __float_as_uint(x);
  u += 0x7fffu + ((u >> 16) & 1u);
  return (u16)(u >> 16);
}
__device__ __forceinline__ u32 cvtpk(float lo, float hi) {
  u32 r;
  asm("v_cvt_pk_bf16_f32 %0, %1, %2" : "=v"(r) : "v"(lo), "v"(hi));
  return r;
}

typedef __attribute__((address_space(1))) const void glob_void;
typedef __attribute__((address_space(3))) void lds_void;
__device__ __forceinline__ void gld16(const void* g, void* s) {
  __builtin_amdgcn_global_load_lds((glob_void*)g, (lds_void*)s, 16, 0, 0);
}

// ---------------------------------------------------------------- convert
__global__ void cvt_bf16(const float4* __restrict__ in, ushort4* __restrict__ out, int n4) {
  int stride = gridDim.x * blockDim.x;
  for (int i = blockIdx.x * blockDim.x + threadIdx.x; i < n4; i += stride) {
    float4 v = in[i];
    ushort4 o;
    o.x = f2b(v.x); o.y = f2b(v.y); o.z = f2b(v.z); o.w = f2b(v.w);
    out[i] = o;
  }
}

// ---------------------------------------------------------------- QKV GEMM
// 256x256 tile, BK=32, 512 thr (8 waves, 2M x 4N, per-wave 128x64).
// Counted-vmcnt pipeline: 4 LDS buffers (t&3), prefetch distance 2,
// ONE barrier + ONE s_waitcnt vmcnt(4) per K-tile (never drains to 0 in
// steady state; tile t+1's 4 loads stay in flight across the barrier).
// LDS 16B-granule XOR-swizzle (phys = logical ^ ((row>>1)&3)), both-sides.
__global__ __launch_bounds__(512) void gemm_qkv(
    const u16* __restrict__ xb, const u16* __restrict__ wb,
    u16* __restrict__ q, u16* __restrict__ k, u16* __restrict__ vt)
{
  __shared__ u16 lA[4][256*32];   // 16 KB per buffer
  __shared__ u16 lB[4][256*32];
  const int tid = threadIdx.x;
  const int lane = tid & 63;
  const int wv = tid >> 6;              // 0..7
  const int wr = wv >> 2, wc = wv & 3;  // 2M x 4N
  const int m0 = blockIdx.x << 8;
  const int by = blockIdx.y;
  const int o0 = by << 8;
  f32x4 acc[8][4] = {};
  const int srow = tid >> 2;            // 0..127 (shot j adds 128)
  const int sb   = (((tid & 3) ^ ((srow >> 1) & 3)) << 4);  // pre-swizzled global granule
  const char* gA0 = (const char*)(xb + (size_t)(m0 + srow) * 768) + sb;
  const char* gB0 = (const char*)(wb + (size_t)(o0 + srow) * 768) + sb;
  char* sA = (char*)lA + tid * 16;
  char* sB = (char*)lB + tid * 16;
  const int frow = lane & 15;
  const int fk   = (((lane >> 4) ^ ((frow >> 1) & 3)) << 4);

  // one tile stage = 4 gld16/thread: A rows [0,128)+[128,256), B same.
  // +196608 = 128 rows * 768 cols * 2B (global); +8192 = half-buffer (LDS).
#define QSTG(t) do { const int kb_ = (t) << 6; const int bo_ = ((t) & 3) << 14; \
    gld16(gA0 + kb_,          sA + bo_); \
    gld16(gA0 + kb_ + 196608, sA + bo_ + 8192); \
    gld16(gB0 + kb_,          sB + bo_); \
    gld16(gB0 + kb_ + 196608, sB + bo_ + 8192); } while (0)

  QSTG(0);
  QSTG(1);
  for (int t = 0; t < 24; ++t) {
    if (t < 23) asm volatile("s_waitcnt vmcnt(4)" ::: "memory");
    else        asm volatile("s_waitcnt vmcnt(0)" ::: "memory");
    __builtin_amdgcn_s_barrier();
    if (t < 22) QSTG(t + 2);
    const char* bA = (const char*)lA + ((t & 3) << 14);
    const char* bB = (const char*)lB + ((t & 3) << 14);
    bf16x8 bfr[4];
#pragma unroll
    for (int n = 0; n < 4; ++n)
      bfr[n] = *(const bf16x8*)(bB + ((wc*64 + n*16 + frow) << 6) + fk);
    __builtin_amdgcn_s_setprio(1);
#pragma unroll
    for (int m = 0; m < 8; ++m) {
      bf16x8 af = *(const bf16x8*)(bA + ((wr*128 + m*16 + frow) << 6) + fk);
#pragma unroll
      for (int n = 0; n < 4; ++n)
        acc[m][n] = MFMA16(af, bfr[n], acc[m][n]);
    }
    __builtin_amdgcn_s_setprio(0);
  }
  const int which = by / 3;             // 9 y-blocks: 3 per q/k/v
  const int ob = (by - which * 3) << 8;
  const float QSCALE = 0.18033688011112042f; // 0.125 * log2(e)
#pragma unroll
  for (int n = 0; n < 4; ++n) {
    const int go = ob + wc*64 + n*16 + frow;
    const int h = go >> 6, d = go & 63;
#pragma unroll
    for (int m = 0; m < 8; ++m) {
      const int gm0 = m0 + wr*128 + m*16 + ((lane >> 4) << 2);
      const int b = gm0 >> 10, nn0 = gm0 & 1023;
      if (which == 2) {
        ushort4 o4;
        o4.x = f2b(acc[m][n][0]); o4.y = f2b(acc[m][n][1]);
        o4.z = f2b(acc[m][n][2]); o4.w = f2b(acc[m][n][3]);
        *(ushort4*)(vt + (((size_t)((b*12 + h)*64 + d)) << 10) + nn0) = o4;
      } else if (which == 0) {
#pragma unroll
        for (int r = 0; r < 4; ++r)
          q[((size_t)((b*12 + h)*1024 + nn0 + r) << 6) + d] = f2b(acc[m][n][r] * QSCALE);
      } else {
#pragma unroll
        for (int r = 0; r < 4; ++r)
          k[((size_t)((b*12 + h)*1024 + nn0 + r) << 6) + d] = f2b(acc[m][n][r]);
      }
    }
  }
}

// ---------------------------------------------------------------- attention
// 8 waves x 32 q-rows = QBLK 256; grid (bh=192, qt=4) -> XCD-grouped.
// Counted-vmcnt pipeline: 4 LDS buffers, distance 2, vmcnt(2) + 1 barrier
// per kv-tile. Wave core: swapped-QK 32x32, defer-max (T13), T12 pack.
__global__ __launch_bounds__(512) void attn_fwd(
    const u16* __restrict__ q, const u16* __restrict__ kk,
    const u16* __restrict__ vt, u16* __restrict__ ao)
{
  __shared__ u16 lK[4][64*64];   // 8 KB per buffer
  __shared__ u16 lV[4][64*64];
  const int tid = threadIdx.x, lane = tid & 63, wv = tid >> 6;
  const int l31 = lane & 31, hh = lane >> 5;
  const int bh = blockIdx.x, qt = blockIdx.y;
  const u16*  qb = q  + ((size_t)bh << 16);
  const char* kg = (const char*)(kk + ((size_t)bh << 16));
  const char* vg = (const char*)(vt + ((size_t)bh << 16));
  const int qrow = (qt << 8) + (wv << 5) + l31;
  bf16x8 qreg[4];
#pragma unroll
  for (int c = 0; c < 4; ++c)
    qreg[c] = *(const bf16x8*)((const char*)qb + (size_t)qrow*128 + c*32 + hh*16);
  f32x16 ot[2] = {};
  float mrun = -1e30f, lrun = 0.f;
  const int o1 = tid << 4;
  const int ko1 = o1 ^ (((o1 >> 7) & 7) << 4);
  const int d1 = o1 >> 7;
  const int vo1 = d1*2048 + ((o1 & 127) ^ ((d1 & 7) << 4));
  char* sK = (char*)lK;
  char* sV = (char*)lV;

#define ATTN_STAGE(t) do { const int bo_ = ((t) & 3) << 13; \
    gld16(kg + ((t) << 13) + ko1, sK + bo_ + o1); \
    gld16(vg + ((t) << 7) + vo1, sV + bo_ + o1); } while (0)

  ATTN_STAGE(0);
  ATTN_STAGE(1);
  for (int t0 = 0; t0 < 16; ++t0) {
    if (t0 < 15) asm volatile("s_waitcnt vmcnt(2)" ::: "memory");
    else         asm volatile("s_waitcnt vmcnt(0)" ::: "memory");
    __builtin_amdgcn_s_barrier();
    if (t0 < 14) ATTN_STAGE(t0 + 2);
    const char* bK = (const char*)lK + ((t0 & 3) << 13);
    const char* bV = (const char*)lV + ((t0 & 3) << 13);
    f32x16 s[2] = {};
#pragma unroll
    for (int tt = 0; tt < 2; ++tt) {
      const int row = (tt << 5) + l31;
      const int rb = row << 7;
      const int sw = (row & 7) << 4;
#pragma unroll
      for (int c = 0; c < 4; ++c) {
        bf16x8 kf = *(const bf16x8*)(bK + rb + (((c << 5) + (hh << 4)) ^ sw));
        s[tt] = MFMA32(kf, qreg[c], s[tt]);
      }
    }
    float mloc = s[0][0];
#pragma unroll
    for (int tt = 0; tt < 2; ++tt)
#pragma unroll
      for (int r = 0; r < 16; ++r) mloc = fmaxf(mloc, s[tt][r]);
    if (!__all(mloc <= mrun + 8.f)) {      // defer-max (T13)
      mloc = fmaxf(mloc, __shfl_xor(mloc, 32));
      const float mnew  = fmaxf(mrun, mloc);
      const float alpha = __builtin_amdgcn_exp2f(mrun - mnew);
      lrun *= alpha;
#pragma unroll
      for (int dt = 0; dt < 2; ++dt)
#pragma unroll
        for (int r = 0; r < 16; ++r) ot[dt][r] *= alpha;
      mrun = mnew;
    }
    float sum = 0.f;
#pragma unroll
    for (int tt = 0; tt < 2; ++tt)
#pragma unroll
      for (int r = 0; r < 16; ++r) {
        s[tt][r] = __builtin_amdgcn_exp2f(s[tt][r] - mrun);
        sum += s[tt][r];
      }
    sum += __shfl_xor(sum, 32);
    lrun += sum;
    bf16x8 pb[4];
#pragma unroll
    for (int tt = 0; tt < 2; ++tt) {
      u32 x0 = cvtpk(s[tt][0],  s[tt][1]);
      u32 y0 = cvtpk(s[tt][4],  s[tt][5]);
      u32 x1 = cvtpk(s[tt][2],  s[tt][3]);
      u32 y1 = cvtpk(s[tt][6],  s[tt][7]);
      asm("v_permlane32_swap_b32 %0, %1" : "+v"(x0), "+v"(y0));
      asm("v_permlane32_swap_b32 %0, %1" : "+v"(x1), "+v"(y1));
      u32 x2 = cvtpk(s[tt][8],  s[tt][9]);
      u32 y2 = cvtpk(s[tt][12], s[tt][13]);
      u32 x3 = cvtpk(s[tt][10], s[tt][11]);
      u32 y3 = cvtpk(s[tt][14], s[tt][15]);
      asm("v_permlane32_swap_b32 %0, %1" : "+v"(x2), "+v"(y2));
      asm("v_permlane32_swap_b32 %0, %1" : "+v"(x3), "+v"(y3));
      union { u32 u[4]; bf16x8 v; } a, b;
      a.u[0] = x0; a.u[1] = x1; a.u[2] = y0; a.u[3] = y1;
      b.u[0] = x2; b.u[1] = x3; b.u[2] = y2; b.u[3] = y3;
      pb[2*tt]     = a.v;
      pb[2*tt + 1] = b.v;
    }
#pragma unroll
    for (int dt = 0; dt < 2; ++dt) {
      const int row = (dt << 5) + l31;
      const int rb = row << 7;
      const int sw = (row & 7) << 4;
#pragma unroll
      for (int cc = 0; cc < 4; ++cc) {
        bf16x8 vf = *(const bf16x8*)(bV + rb + (((cc << 5) + (hh << 4)) ^ sw));
        ot[dt] = MFMA32(vf, pb[cc], ot[dt]);
      }
    }
  }
  const float linv = 1.f / lrun;
  const int b = bh / 12, h = bh - b * 12;
  u16* po = ao + ((size_t)(b*1024 + qrow)) * 768 + h*64;
#pragma unroll
  for (int dt = 0; dt < 2; ++dt) {
#pragma unroll
    for (int g = 0; g < 4; ++g) {
      ushort4 o4;
      o4.x = f2b(ot[dt][4*g + 0] * linv);
      o4.y = f2b(ot[dt][4*g + 1] * linv);
      o4.z = f2b(ot[dt][4*g + 2] * linv);
      o4.w = f2b(ot[dt][4*g + 3] * linv);
      *(ushort4*)(po + dt*32 + g*8 + hh*4) = o4;
    }
  }
}

// ---------------------------------------------------------------- proj GEMM
// 128x128 tile; counted-vmcnt pipeline (4 buffers, distance 2, vmcnt(4),
// one barrier per K-tile).
__global__ __launch_bounds__(256) void gemm_proj(
    const u16* __restrict__ ab, const u16* __restrict__ wb,
    const float* __restrict__ bias, float* __restrict__ out)
{
  __shared__ u16 lA[4][128*32];   // 8 KB per buffer
  __shared__ u16 lB[4][128*32];
  const int tid = threadIdx.x;
  const int lane = tid & 63;
  const int wv = tid >> 6;
  const int wr = wv >> 1, wc = wv & 1;
  const int m0 = blockIdx.x << 7;
  const int o0 = blockIdx.y << 7;
  f32x4 acc[4][4] = {};
  const int srow = tid >> 2;
  const int sb   = (((tid & 3) ^ ((srow >> 1) & 3)) << 4);
  const char* gA0 = (const char*)(ab + (size_t)(m0 + srow)      * 768) + sb;
  const char* gA1 = (const char*)(ab + (size_t)(m0 + 64 + srow) * 768) + sb;
  const char* gB0 = (const char*)(wb + (size_t)(o0 + srow)      * 768) + sb;
  const char* gB1 = (const char*)(wb + (size_t)(o0 + 64 + srow) * 768) + sb;
  char* sA = (char*)lA + tid * 16;
  char* sB = (char*)lB + tid * 16;
  const int frow = lane & 15;
  const int fk   = (((lane >> 4) ^ ((frow >> 1) & 3)) << 4);

#define PSTG(t) do { const int kb_ = (t) << 6; const int bo_ = ((t) & 3) << 13; \
    gld16(gA0 + kb_, sA + bo_); gld16(gA1 + kb_, sA + bo_ + 4096); \
    gld16(gB0 + kb_, sB + bo_); gld16(gB1 + kb_, sB + bo_ + 4096); } while (0)

  PSTG(0);
  PSTG(1);
  for (int t = 0; t < 24; ++t) {
    if (t < 23) asm volatile("s_waitcnt vmcnt(4)" ::: "memory");
    else        asm volatile("s_waitcnt vmcnt(0)" ::: "memory");
    __builtin_amdgcn_s_barrier();
    if (t < 22) PSTG(t + 2);
    const char* bA = (const char*)lA + ((t & 3) << 13);
    const char* bB = (const char*)lB + ((t & 3) << 13);
    bf16x8 af[4], bfr[4];
#pragma unroll
    for (int m = 0; m < 4; ++m)
      af[m] = *(const bf16x8*)(bA + ((wr*64 + m*16 + frow) << 6) + fk);
#pragma unroll
    for (int n = 0; n < 4; ++n)
      bfr[n] = *(const bf16x8*)(bB + ((wc*64 + n*16 + frow) << 6) + fk);
    __builtin_amdgcn_s_setprio(1);
#pragma unroll
    for (int m = 0; m < 4; ++m)
#pragma unroll
      for (int n = 0; n < 4; ++n)
        acc[m][n] = MFMA16(af[m], bfr[n], acc[m][n]);
    __builtin_amdgcn_s_setprio(0);
  }
#pragma unroll
  for (int n = 0; n < 4; ++n) {
    const int go = o0 + wc*64 + n*16 + (lane & 15);
    const float bv = bias[go];
#pragma unroll
    for (int m = 0; m < 4; ++m) {
#pragma unroll
      for (int r = 0; r < 4; ++r) {
        const int gm = m0 + wr*64 + m*16 + ((lane >> 4) << 2) + r;
        out[(size_t)gm * 768 + go] = acc[m][n][r] + bv;
      }
    }
  }
}

// ---------------------------------------------------------------- launch
extern "C" void kernel_launch(void* const* d_in, const int* in_sizes, int n_in,
                              void* d_out, int out_size, void* d_ws, size_t ws_size,
                              hipStream_t stream)
{
  (void)in_sizes; (void)n_in; (void)out_size; (void)ws_size;
  const float* x  = (const float*)d_in[0];
  const float* wq = (const float*)d_in[1];
  const float* wp = (const float*)d_in[2];
  const float* bp = (const float*)d_in[3];
  float* out = (float*)d_out;
  char* ws = (char*)d_ws;
  u16* xb     = (u16*)(ws);              // 25,165,824  x bf16 [16384][768]
  u16* wqkvb  = (u16*)(ws + 25165824);   //  3,538,944  w_qkv bf16
  u16* wprojb = (u16*)(ws + 28704768);   //  1,179,648  w_proj bf16
  u16* qa     = (u16*)(ws + 29884416);   // 25,165,824  q  [192][1024][64] (pre-scaled)
  u16* ka     = (u16*)(ws + 55050240);   // 25,165,824  k  [192][1024][64]
  u16* vta    = (u16*)(ws + 80216064);   // 25,165,824  v^T[192][64][1024]
  u16* ao     = xb;                      // alias: xb dead after gemm_qkv

  cvt_bf16<<<2048, 256, 0, stream>>>((const float4*)x,  (ushort4*)xb,     3145728);
  cvt_bf16<<<1024, 256, 0, stream>>>((const float4*)wq, (ushort4*)wqkvb,   442368);
  cvt_bf16<<< 576, 256, 0, stream>>>((const float4*)wp, (ushort4*)wprojb,  147456);
  gemm_qkv<<<dim3(64, 9), 512, 0, stream>>>(xb, wqkvb, qa, ka, vta);
  attn_fwd<<<dim3(192, 4), 512, 0, stream>>>(qa, ka, vta, ao);
  gemm_proj<<<dim3(128, 6), 256, 0, stream>>>(ao, wprojb, bp, out);
}

// Round 8
// 208.800 us; speedup vs baseline: 1.1765x; 1.1765x over previous
//
#include <hip/hip_runtime.h>
#include <hip/hip_bf16.h>
#include <stdint.h>

typedef unsigned short u16;
typedef unsigned int   u32;
typedef short bf16x8 __attribute__((ext_vector_type(8)));
typedef float f32x4  __attribute__((ext_vector_type(4)));
typedef float f32x16 __attribute__((ext_vector_type(16)));

#define MFMA16(A,B,C) __builtin_amdgcn_mfma_f32_16x16x32_bf16((A),(B),(C),0,0,0)
#define MFMA32(A,B,C) __builtin_amdgcn_mfma_f32_32x32x16_bf16((A),(B),(C),0,0,0)

// fp32 -> bf16 round-to-nearest-even
__device__ __forceinline__ u16 f2b(float x) {
  u32 u = __float_as_uint(x);
  u += 0x7fffu + ((u >> 16) & 1u);
  return (u16)(u >> 16);
}
__device__ __forceinline__ u32 cvtpk(float lo, float hi) {
  u32 r;
  asm("v_cvt_pk_bf16_f32 %0, %1, %2" : "=v"(r) : "v"(lo), "v"(hi));
  return r;
}

typedef __attribute__((address_space(1))) const void glob_void;
typedef __attribute__((address_space(3))) void lds_void;
__device__ __forceinline__ void gld16(const void* g, void* s) {
  __builtin_amdgcn_global_load_lds((glob_void*)g, (lds_void*)s, 16, 0, 0);
}

// ---------------------------------------------------------------- convert
__global__ void cvt_bf16(const float4* __restrict__ in, ushort4* __restrict__ out, int n4) {
  int stride = gridDim.x * blockDim.x;
  for (int i = blockIdx.x * blockDim.x + threadIdx.x; i < n4; i += stride) {
    float4 v = in[i];
    ushort4 o;
    o.x = f2b(v.x); o.y = f2b(v.y); o.z = f2b(v.z); o.w = f2b(v.w);
    out[i] = o;
  }
}

// ---------------------------------------------------------------- QKV GEMM
// 8-phase m201-template port: 256x256 tile, BK=64, 512 thr (8 waves, 2Mx4N,
// per-wave 128x64 output). LDS = 2 dbuf x (A[256][64] + B[256][64]) bf16 =
// 128 KB. Per K-tile: 4 phases (mh,ks), each {8 ds_read_b128 || 2
// global_load_lds of next tile -> barrier -> setprio+16 MFMA -> barrier}.
// Counted waits ONLY at phase0 (vmcnt(2)) and phase2 (vmcnt(4); last tile 0).
// Issue order per tile: B0,B1 | B2,B3 | A0,A2 | A1,A3  (chunks = 64-row
// stages). Ledger: p0 outstanding 8 -> keep A1,A3 in flight = vmcnt(2);
// p2 outstanding 6 -> drain A1,A3 = vmcnt(4).
// Swizzle (stride-128B rows): phys_granule = logical ^ (row&7); staging
// pre-swizzles the GLOBAL source column (LDS dest stays linear for gld16),
// reads apply the same XOR -> 2-way bank aliasing (free).
__global__ __launch_bounds__(512) void gemm_qkv(
    const u16* __restrict__ xb, const u16* __restrict__ wb,
    u16* __restrict__ q, u16* __restrict__ k, u16* __restrict__ vt)
{
  __shared__ u16 lA[2][256*64];   // 32 KB per buffer
  __shared__ u16 lB[2][256*64];
  const int tid = threadIdx.x;
  const int lane = tid & 63;
  const int wv = tid >> 6;              // 0..7
  const int wr = wv >> 2, wc = wv & 3;  // 2M x 4N
  const int m0 = blockIdx.x << 8;
  const int by = blockIdx.y;
  const int o0 = by << 8;
  f32x4 acc[8][4] = {};
  // staging: thread -> (row srow in 64-row chunk, granule tid&7), src col
  // pre-swizzled so linear LDS dest holds the swizzled layout.
  const int srow = tid >> 3;                       // 0..63
  const int sg   = (((tid & 7) ^ (srow & 7)) << 4);
  const char* gA = (const char*)xb + (size_t)(m0 + srow) * 1536 + sg;
  const char* gB = (const char*)wb + (size_t)(o0 + srow) * 1536 + sg;
  char* sA = (char*)lA + tid * 16;
  char* sB = (char*)lB + tid * 16;
  // fragment reads: row = (wr*128 + mh*64 + i*16 + frow), row&7 == frow&7
  const int frow = lane & 15, hh = lane >> 4;      // hh 0..3
  const int swz = (frow & 7) << 4;
  const int fc0 = ((hh << 4)      ) ^ swz;         // ks=0 granule byte
  const int fc1 = ((hh << 4) + 64 ) ^ swz;         // ks=1

  // chunk c covers tile-rows [c*64, c*64+64); global +98304 = 64 rows * 1536 B
#define STGA(t1, c) gld16(gA + (size_t)(c)*98304 + (size_t)(t1)*128, \
                          sA + (((t1) & 1) << 15) + ((c) << 13))
#define STGB(t1, c) gld16(gB + (size_t)(c)*98304 + (size_t)(t1)*128, \
                          sB + (((t1) & 1) << 15) + ((c) << 13))

#define QPHASE(MH, FC, STG_PAIR) do { \
    bf16x8 af_[4], bf_[4]; \
    _Pragma("unroll") \
    for (int i_ = 0; i_ < 4; ++i_) \
      af_[i_] = *(const bf16x8*)(bA + ((wr*128 + (MH)*64 + i_*16 + frow) << 7) + (FC)); \
    _Pragma("unroll") \
    for (int n_ = 0; n_ < 4; ++n_) \
      bf_[n_] = *(const bf16x8*)(bB + ((wc*64 + n_*16 + frow) << 7) + (FC)); \
    if (st) { STG_PAIR; } \
    __builtin_amdgcn_s_barrier(); \
    __builtin_amdgcn_s_setprio(1); \
    _Pragma("unroll") \
    for (int i_ = 0; i_ < 4; ++i_) \
      _Pragma("unroll") \
      for (int n_ = 0; n_ < 4; ++n_) \
        acc[(MH)*4 + i_][n_] = MFMA16(af_[i_], bf_[n_], acc[(MH)*4 + i_][n_]); \
    __builtin_amdgcn_s_setprio(0); \
  } while (0)

  // prologue: tile 0, canonical issue order
  STGB(0, 0); STGB(0, 1); STGB(0, 2); STGB(0, 3);
  STGA(0, 0); STGA(0, 2); STGA(0, 1); STGA(0, 3);

  for (int t = 0; t < 12; ++t) {
    const char* bA = (const char*)lA + ((t & 1) << 15);
    const char* bB = (const char*)lB + ((t & 1) << 15);
    const bool st = (t < 11);
    const int tn = t + 1;
    // phase 0 (mh=0, ks=0)
    asm volatile("s_waitcnt vmcnt(2)" ::: "memory");
    __builtin_amdgcn_s_barrier();
    QPHASE(0, fc0, STGB(tn, 0); STGB(tn, 1));
    // phase 1 (mh=0, ks=1)
    __builtin_amdgcn_s_barrier();
    QPHASE(0, fc1, STGB(tn, 2); STGB(tn, 3));
    // phase 2 (mh=1, ks=0)
    if (st) asm volatile("s_waitcnt vmcnt(4)" ::: "memory");
    else    asm volatile("s_waitcnt vmcnt(0)" ::: "memory");
    __builtin_amdgcn_s_barrier();
    QPHASE(1, fc0, STGA(tn, 0); STGA(tn, 2));
    // phase 3 (mh=1, ks=1)
    __builtin_amdgcn_s_barrier();
    QPHASE(1, fc1, STGA(tn, 1); STGA(tn, 3));
  }

  const int which = by / 3;             // 9 y-blocks: 3 per q/k/v
  const int ob = (by - which * 3) << 8;
  const float QSCALE = 0.18033688011112042f; // 0.125 * log2(e)
#pragma unroll
  for (int n = 0; n < 4; ++n) {
    const int go = ob + wc*64 + n*16 + frow;
    const int h = go >> 6, d = go & 63;
#pragma unroll
    for (int m = 0; m < 8; ++m) {
      const int gm0 = m0 + wr*128 + m*16 + ((lane >> 4) << 2);
      const int b = gm0 >> 10, nn0 = gm0 & 1023;
      if (which == 2) {
        ushort4 o4;
        o4.x = f2b(acc[m][n][0]); o4.y = f2b(acc[m][n][1]);
        o4.z = f2b(acc[m][n][2]); o4.w = f2b(acc[m][n][3]);
        *(ushort4*)(vt + (((size_t)((b*12 + h)*64 + d)) << 10) + nn0) = o4;
      } else if (which == 0) {
#pragma unroll
        for (int r = 0; r < 4; ++r)
          q[((size_t)((b*12 + h)*1024 + nn0 + r) << 6) + d] = f2b(acc[m][n][r] * QSCALE);
      } else {
#pragma unroll
        for (int r = 0; r < 4; ++r)
          k[((size_t)((b*12 + h)*1024 + nn0 + r) << 6) + d] = f2b(acc[m][n][r]);
      }
    }
  }
}

// ---------------------------------------------------------------- attention
// r6-proven version: 8 waves x 32 q-rows = QBLK 256; grid (bh=192, qt=4)
// XCD-grouped; K/V 2-buffer T3-min pipeline (drain-0); swapped-QK 32x32;
// defer-max (T13); cvt_pk+permlane (T12).
__global__ __launch_bounds__(512) void attn_fwd(
    const u16* __restrict__ q, const u16* __restrict__ kk,
    const u16* __restrict__ vt, u16* __restrict__ ao)
{
  __shared__ u16 lK[2][64*64];
  __shared__ u16 lV[2][64*64];
  const int tid = threadIdx.x, lane = tid & 63, wv = tid >> 6;
  const int l31 = lane & 31, hh = lane >> 5;
  const int bh = blockIdx.x, qt = blockIdx.y;
  const u16*  qb = q  + ((size_t)bh << 16);
  const char* kg = (const char*)(kk + ((size_t)bh << 16));
  const char* vg = (const char*)(vt + ((size_t)bh << 16));
  const int qrow = (qt << 8) + (wv << 5) + l31;
  bf16x8 qreg[4];
#pragma unroll
  for (int c = 0; c < 4; ++c)
    qreg[c] = *(const bf16x8*)((const char*)qb + (size_t)qrow*128 + c*32 + hh*16);
  f32x16 ot[2] = {};
  float mrun = -1e30f, lrun = 0.f;
  const int o1 = tid << 4;
  const int ko1 = o1 ^ (((o1 >> 7) & 7) << 4);
  const int d1 = o1 >> 7;
  const int vo1 = d1*2048 + ((o1 & 127) ^ ((d1 & 7) << 4));
  char* sK = (char*)lK;
  char* sV = (char*)lV;

#define ATTN_STAGE(buf, t) do { const int bo_ = (buf) << 13; \
    gld16(kg + ((t) << 13) + ko1, sK + bo_ + o1); \
    gld16(vg + ((t) << 7) + vo1, sV + bo_ + o1); } while (0)

  ATTN_STAGE(0, 0);
  asm volatile("s_waitcnt vmcnt(0) lgkmcnt(0)" ::: "memory");
  __builtin_amdgcn_s_barrier();
  for (int t0 = 0; t0 < 16; ++t0) {
    const int cur = t0 & 1;
    if (t0 < 15) ATTN_STAGE(cur ^ 1, t0 + 1);
    const char* bK = (const char*)lK + (cur << 13);
    const char* bV = (const char*)lV + (cur << 13);
    f32x16 s[2] = {};
#pragma unroll
    for (int tt = 0; tt < 2; ++tt) {
      const int row = (tt << 5) + l31;
      const int rb = row << 7;
      const int sw = (row & 7) << 4;
#pragma unroll
      for (int c = 0; c < 4; ++c) {
        bf16x8 kf = *(const bf16x8*)(bK + rb + (((c << 5) + (hh << 4)) ^ sw));
        s[tt] = MFMA32(kf, qreg[c], s[tt]);
      }
    }
    float mloc = s[0][0];
#pragma unroll
    for (int tt = 0; tt < 2; ++tt)
#pragma unroll
      for (int r = 0; r < 16; ++r) mloc = fmaxf(mloc, s[tt][r]);
    if (!__all(mloc <= mrun + 8.f)) {      // defer-max (T13)
      mloc = fmaxf(mloc, __shfl_xor(mloc, 32));
      const float mnew  = fmaxf(mrun, mloc);
      const float alpha = __builtin_amdgcn_exp2f(mrun - mnew);
      lrun *= alpha;
#pragma unroll
      for (int dt = 0; dt < 2; ++dt)
#pragma unroll
        for (int r = 0; r < 16; ++r) ot[dt][r] *= alpha;
      mrun = mnew;
    }
    float sum = 0.f;
#pragma unroll
    for (int tt = 0; tt < 2; ++tt)
#pragma unroll
      for (int r = 0; r < 16; ++r) {
        s[tt][r] = __builtin_amdgcn_exp2f(s[tt][r] - mrun);
        sum += s[tt][r];
      }
    sum += __shfl_xor(sum, 32);
    lrun += sum;
    bf16x8 pb[4];
#pragma unroll
    for (int tt = 0; tt < 2; ++tt) {
      u32 x0 = cvtpk(s[tt][0],  s[tt][1]);
      u32 y0 = cvtpk(s[tt][4],  s[tt][5]);
      u32 x1 = cvtpk(s[tt][2],  s[tt][3]);
      u32 y1 = cvtpk(s[tt][6],  s[tt][7]);
      asm("v_permlane32_swap_b32 %0, %1" : "+v"(x0), "+v"(y0));
      asm("v_permlane32_swap_b32 %0, %1" : "+v"(x1), "+v"(y1));
      u32 x2 = cvtpk(s[tt][8],  s[tt][9]);
      u32 y2 = cvtpk(s[tt][12], s[tt][13]);
      u32 x3 = cvtpk(s[tt][10], s[tt][11]);
      u32 y3 = cvtpk(s[tt][14], s[tt][15]);
      asm("v_permlane32_swap_b32 %0, %1" : "+v"(x2), "+v"(y2));
      asm("v_permlane32_swap_b32 %0, %1" : "+v"(x3), "+v"(y3));
      union { u32 u[4]; bf16x8 v; } a, b;
      a.u[0] = x0; a.u[1] = x1; a.u[2] = y0; a.u[3] = y1;
      b.u[0] = x2; b.u[1] = x3; b.u[2] = y2; b.u[3] = y3;
      pb[2*tt]     = a.v;
      pb[2*tt + 1] = b.v;
    }
#pragma unroll
    for (int dt = 0; dt < 2; ++dt) {
      const int row = (dt << 5) + l31;
      const int rb = row << 7;
      const int sw = (row & 7) << 4;
#pragma unroll
      for (int cc = 0; cc < 4; ++cc) {
        bf16x8 vf = *(const bf16x8*)(bV + rb + (((cc << 5) + (hh << 4)) ^ sw));
        ot[dt] = MFMA32(vf, pb[cc], ot[dt]);
      }
    }
    asm volatile("s_waitcnt vmcnt(0) lgkmcnt(0)" ::: "memory");
    __builtin_amdgcn_s_barrier();
  }
  const float linv = 1.f / lrun;
  const int b = bh / 12, h = bh - b * 12;
  u16* po = ao + ((size_t)(b*1024 + qrow)) * 768 + h*64;
#pragma unroll
  for (int dt = 0; dt < 2; ++dt) {
#pragma unroll
    for (int g = 0; g < 4; ++g) {
      ushort4 o4;
      o4.x = f2b(ot[dt][4*g + 0] * linv);
      o4.y = f2b(ot[dt][4*g + 1] * linv);
      o4.z = f2b(ot[dt][4*g + 2] * linv);
      o4.w = f2b(ot[dt][4*g + 3] * linv);
      *(ushort4*)(po + dt*32 + g*8 + hh*4) = o4;
    }
  }
}

// ---------------------------------------------------------------- proj GEMM
// r6-proven version: 128x128 tile, 2-buffer drain-0 pipeline.
__global__ __launch_bounds__(256) void gemm_proj(
    const u16* __restrict__ ab, const u16* __restrict__ wb,
    const float* __restrict__ bias, float* __restrict__ out)
{
  __shared__ u16 lAp[2][128*32];
  __shared__ u16 lBp[2][128*32];
  const int tid = threadIdx.x;
  const int lane = tid & 63;
  const int wv = tid >> 6;
  const int wr = wv >> 1, wc = wv & 1;
  const int m0 = blockIdx.x << 7;
  const int o0 = blockIdx.y << 7;
  f32x4 acc[4][4] = {};
  const int srow = tid >> 2;
  const int sb   = (((tid & 3) ^ ((srow >> 1) & 3)) << 4);
  const char* gA0 = (const char*)(ab + (size_t)(m0 + srow)      * 768) + sb;
  const char* gA1 = (const char*)(ab + (size_t)(m0 + 64 + srow) * 768) + sb;
  const char* gB0 = (const char*)(wb + (size_t)(o0 + srow)      * 768) + sb;
  const char* gB1 = (const char*)(wb + (size_t)(o0 + 64 + srow) * 768) + sb;
  char* sAp = (char*)lAp + tid * 16;
  char* sBp = (char*)lBp + tid * 16;
  const int frow = lane & 15;
  const int fk   = (((lane >> 4) ^ ((frow >> 1) & 3)) << 4);

#define PSTG(buf, kt) do { const int kb_ = (kt) << 6; const int bo_ = (buf) << 13; \
    gld16(gA0 + kb_, sAp + bo_); gld16(gA1 + kb_, sAp + bo_ + 4096); \
    gld16(gB0 + kb_, sBp + bo_); gld16(gB1 + kb_, sBp + bo_ + 4096); } while (0)

  PSTG(0, 0);
  asm volatile("s_waitcnt vmcnt(0) lgkmcnt(0)" ::: "memory");
  __builtin_amdgcn_s_barrier();
  for (int kt = 0; kt < 24; ++kt) {
    const int cur = kt & 1;
    if (kt < 23) PSTG(cur ^ 1, kt + 1);
    const char* bA = (const char*)lAp + (cur << 13);
    const char* bB = (const char*)lBp + (cur << 13);
    bf16x8 af[4], bfr[4];
#pragma unroll
    for (int m = 0; m < 4; ++m)
      af[m] = *(const bf16x8*)(bA + ((wr*64 + m*16 + frow) << 6) + fk);
#pragma unroll
    for (int n = 0; n < 4; ++n)
      bfr[n] = *(const bf16x8*)(bB + ((wc*64 + n*16 + frow) << 6) + fk);
#pragma unroll
    for (int m = 0; m < 4; ++m)
#pragma unroll
      for (int n = 0; n < 4; ++n)
        acc[m][n] = MFMA16(af[m], bfr[n], acc[m][n]);
    asm volatile("s_waitcnt vmcnt(0) lgkmcnt(0)" ::: "memory");
    __builtin_amdgcn_s_barrier();
  }
#pragma unroll
  for (int n = 0; n < 4; ++n) {
    const int go = o0 + wc*64 + n*16 + (lane & 15);
    const float bv = bias[go];
#pragma unroll
    for (int m = 0; m < 4; ++m) {
#pragma unroll
      for (int r = 0; r < 4; ++r) {
        const int gm = m0 + wr*64 + m*16 + ((lane >> 4) << 2) + r;
        out[(size_t)gm * 768 + go] = acc[m][n][r] + bv;
      }
    }
  }
}

// ---------------------------------------------------------------- launch
extern "C" void kernel_launch(void* const* d_in, const int* in_sizes, int n_in,
                              void* d_out, int out_size, void* d_ws, size_t ws_size,
                              hipStream_t stream)
{
  (void)in_sizes; (void)n_in; (void)out_size; (void)ws_size;
  const float* x  = (const float*)d_in[0];
  const float* wq = (const float*)d_in[1];
  const float* wp = (const float*)d_in[2];
  const float* bp = (const float*)d_in[3];
  float* out = (float*)d_out;
  char* ws = (char*)d_ws;
  u16* xb     = (u16*)(ws);              // 25,165,824  x bf16 [16384][768]
  u16* wqkvb  = (u16*)(ws + 25165824);   //  3,538,944  w_qkv bf16
  u16* wprojb = (u16*)(ws + 28704768);   //  1,179,648  w_proj bf16
  u16* qa     = (u16*)(ws + 29884416);   // 25,165,824  q  [192][1024][64] (pre-scaled)
  u16* ka     = (u16*)(ws + 55050240);   // 25,165,824  k  [192][1024][64]
  u16* vta    = (u16*)(ws + 80216064);   // 25,165,824  v^T[192][64][1024]
  u16* ao     = xb;                      // alias: xb dead after gemm_qkv

  cvt_bf16<<<2048, 256, 0, stream>>>((const float4*)x,  (ushort4*)xb,     3145728);
  cvt_bf16<<<1024, 256, 0, stream>>>((const float4*)wq, (ushort4*)wqkvb,   442368);
  cvt_bf16<<< 576, 256, 0, stream>>>((const float4*)wp, (ushort4*)wprojb,  147456);
  gemm_qkv<<<dim3(64, 9), 512, 0, stream>>>(xb, wqkvb, qa, ka, vta);
  attn_fwd<<<dim3(192, 4), 512, 0, stream>>>(qa, ka, vta, ao);
  gemm_proj<<<dim3(128, 6), 256, 0, stream>>>(ao, wprojb, bp, out);
}

// Round 10
// 206.872 us; speedup vs baseline: 1.1875x; 1.0093x over previous
//
#include <hip/hip_runtime.h>
#include <hip/hip_bf16.h>
#include <stdint.h>

typedef unsigned short u16;
typedef unsigned int   u32;
typedef short bf16x8 __attribute__((ext_vector_type(8)));
typedef float f32x4  __attribute__((ext_vector_type(4)));
typedef float f32x16 __attribute__((ext_vector_type(16)));

#define MFMA16(A,B,C) __builtin_amdgcn_mfma_f32_16x16x32_bf16((A),(B),(C),0,0,0)
#define MFMA32(A,B,C) __builtin_amdgcn_mfma_f32_32x32x16_bf16((A),(B),(C),0,0,0)

// fp32 -> bf16 round-to-nearest-even
__device__ __forceinline__ u16 f2b(float x) {
  u32 u = __float_as_uint(x);
  u += 0x7fffu + ((u >> 16) & 1u);
  return (u16)(u >> 16);
}
__device__ __forceinline__ u32 cvtpk(float lo, float hi) {
  u32 r;
  asm("v_cvt_pk_bf16_f32 %0, %1, %2" : "=v"(r) : "v"(lo), "v"(hi));
  return r;
}

typedef __attribute__((address_space(1))) const void glob_void;
typedef __attribute__((address_space(3))) void lds_void;
__device__ __forceinline__ void gld16(const void* g, void* s) {
  __builtin_amdgcn_global_load_lds((glob_void*)g, (lds_void*)s, 16, 0, 0);
}

// ---------------------------------------------------------------- convert
__global__ void cvt_bf16(const float4* __restrict__ in, ushort4* __restrict__ out, int n4) {
  int stride = gridDim.x * blockDim.x;
  for (int i = blockIdx.x * blockDim.x + threadIdx.x; i < n4; i += stride) {
    float4 v = in[i];
    ushort4 o;
    o.x = f2b(v.x); o.y = f2b(v.y); o.z = f2b(v.z); o.w = f2b(v.w);
    out[i] = o;
  }
}

// ---------------------------------------------------------------- Q/K GEMM
// r6-proven 128x128 2-phase K-loop. MFMA operands SWAPPED (D = W · X^T):
// D[row=o][col=seq] -> each lane holds 4 consecutive d for one seq row ->
// epilogue = 16 aligned ushort4 stores (vs 64 scalar 2B). Fragment reads
// identical; products identical. by 0..5 -> q (pre-scaled), by 6..11 -> k.
__global__ __launch_bounds__(256) void gemm_qk(
    const u16* __restrict__ xb, const u16* __restrict__ wb,
    u16* __restrict__ q, u16* __restrict__ k)
{
  __shared__ u16 lA[2][128*32];
  __shared__ u16 lB[2][128*32];
  const int tid = threadIdx.x;
  const int lane = tid & 63;
  const int wv = tid >> 6;
  const int wr = wv >> 1, wc = wv & 1;
  const int m0 = blockIdx.x << 7;
  const int by = blockIdx.y;
  const int isq = by < 6;
  const int o0 = by << 7;                       // col in [0,1536)
  f32x4 acc[4][4] = {};
  const int srow = tid >> 2;
  const int sb   = (((tid & 3) ^ ((srow >> 1) & 3)) << 4);
  const char* gA0 = (const char*)(xb + (size_t)(m0 + srow)      * 768) + sb;
  const char* gA1 = (const char*)(xb + (size_t)(m0 + 64 + srow) * 768) + sb;
  const char* gB0 = (const char*)(wb + (size_t)(o0 + srow)      * 768) + sb;
  const char* gB1 = (const char*)(wb + (size_t)(o0 + 64 + srow) * 768) + sb;
  char* sA = (char*)lA + tid * 16;
  char* sB = (char*)lB + tid * 16;
  const int frow = lane & 15;
  const int fk   = (((lane >> 4) ^ ((frow >> 1) & 3)) << 4);

#define KSTG(buf, kt) do { const int kb_ = (kt) << 6; const int bo_ = (buf) << 13; \
    gld16(gA0 + kb_, sA + bo_); gld16(gA1 + kb_, sA + bo_ + 4096); \
    gld16(gB0 + kb_, sB + bo_); gld16(gB1 + kb_, sB + bo_ + 4096); } while (0)

  KSTG(0, 0);
  asm volatile("s_waitcnt vmcnt(0) lgkmcnt(0)" ::: "memory");
  __builtin_amdgcn_s_barrier();
  for (int kt = 0; kt < 24; ++kt) {
    const int cur = kt & 1;
    if (kt < 23) KSTG(cur ^ 1, kt + 1);
    const char* bA = (const char*)lA + (cur << 13);
    const char* bB = (const char*)lB + (cur << 13);
    bf16x8 af[4], bfr[4];
#pragma unroll
    for (int m = 0; m < 4; ++m)
      af[m] = *(const bf16x8*)(bA + ((wr*64 + m*16 + frow) << 6) + fk);
#pragma unroll
    for (int n = 0; n < 4; ++n)
      bfr[n] = *(const bf16x8*)(bB + ((wc*64 + n*16 + frow) << 6) + fk);
#pragma unroll
    for (int m = 0; m < 4; ++m)
#pragma unroll
      for (int n = 0; n < 4; ++n)
        acc[m][n] = MFMA16(bfr[n], af[m], acc[m][n]);   // SWAPPED
    asm volatile("s_waitcnt vmcnt(0) lgkmcnt(0)" ::: "memory");
    __builtin_amdgcn_s_barrier();
  }
  const int ob = (by - (isq ? 0 : 6)) << 7;      // col within q or k [0,768)
  const float scale = isq ? 0.18033688011112042f : 1.0f; // q: 0.125*log2(e)
  u16* dst = isq ? q : k;
  const int hh4 = (lane >> 4) << 2;
#pragma unroll
  for (int n = 0; n < 4; ++n) {
    const int go = ob + wc*64 + n*16 + hh4;      // o (head*64+d), d0 mult of 4
    const int h = go >> 6, d0 = go & 63;
#pragma unroll
    for (int m = 0; m < 4; ++m) {
      const int gm = m0 + wr*64 + m*16 + frow;   // seq index (col=lane&15)
      const int b = gm >> 10, nn = gm & 1023;
      ushort4 o4;
      o4.x = f2b(acc[m][n][0] * scale);
      o4.y = f2b(acc[m][n][1] * scale);
      o4.z = f2b(acc[m][n][2] * scale);
      o4.w = f2b(acc[m][n][3] * scale);
      *(ushort4*)(dst + (((size_t)((b*12 + h)*1024 + nn)) << 6) + d0) = o4;
    }
  }
}

// ---------------------------------------------------------------- V GEMM
// r6-proven 128x128 2-phase K-loop, normal operand order: r varies nn ->
// ushort4 into vt[d][nn]. by 0..5 -> w cols [1536, 2304).
__global__ __launch_bounds__(256) void gemm_v(
    const u16* __restrict__ xb, const u16* __restrict__ wb,
    u16* __restrict__ vt)
{
  __shared__ u16 lA[2][128*32];
  __shared__ u16 lB[2][128*32];
  const int tid = threadIdx.x;
  const int lane = tid & 63;
  const int wv = tid >> 6;
  const int wr = wv >> 1, wc = wv & 1;
  const int m0 = blockIdx.x << 7;
  const int by = blockIdx.y;
  const int o0 = 1536 + (by << 7);
  f32x4 acc[4][4] = {};
  const int srow = tid >> 2;
  const int sb   = (((tid & 3) ^ ((srow >> 1) & 3)) << 4);
  const char* gA0 = (const char*)(xb + (size_t)(m0 + srow)      * 768) + sb;
  const char* gA1 = (const char*)(xb + (size_t)(m0 + 64 + srow) * 768) + sb;
  const char* gB0 = (const char*)(wb + (size_t)(o0 + srow)      * 768) + sb;
  const char* gB1 = (const char*)(wb + (size_t)(o0 + 64 + srow) * 768) + sb;
  char* sA = (char*)lA + tid * 16;
  char* sB = (char*)lB + tid * 16;
  const int frow = lane & 15;
  const int fk   = (((lane >> 4) ^ ((frow >> 1) & 3)) << 4);

#define VSTG(buf, kt) do { const int kb_ = (kt) << 6; const int bo_ = (buf) << 13; \
    gld16(gA0 + kb_, sA + bo_); gld16(gA1 + kb_, sA + bo_ + 4096); \
    gld16(gB0 + kb_, sB + bo_); gld16(gB1 + kb_, sB + bo_ + 4096); } while (0)

  VSTG(0, 0);
  asm volatile("s_waitcnt vmcnt(0) lgkmcnt(0)" ::: "memory");
  __builtin_amdgcn_s_barrier();
  for (int kt = 0; kt < 24; ++kt) {
    const int cur = kt & 1;
    if (kt < 23) VSTG(cur ^ 1, kt + 1);
    const char* bA = (const char*)lA + (cur << 13);
    const char* bB = (const char*)lB + (cur << 13);
    bf16x8 af[4], bfr[4];
#pragma unroll
    for (int m = 0; m < 4; ++m)
      af[m] = *(const bf16x8*)(bA + ((wr*64 + m*16 + frow) << 6) + fk);
#pragma unroll
    for (int n = 0; n < 4; ++n)
      bfr[n] = *(const bf16x8*)(bB + ((wc*64 + n*16 + frow) << 6) + fk);
#pragma unroll
    for (int m = 0; m < 4; ++m)
#pragma unroll
      for (int n = 0; n < 4; ++n)
        acc[m][n] = MFMA16(af[m], bfr[n], acc[m][n]);
    asm volatile("s_waitcnt vmcnt(0) lgkmcnt(0)" ::: "memory");
    __builtin_amdgcn_s_barrier();
  }
  const int ob = by << 7;                        // col within v [0,768)
#pragma unroll
  for (int n = 0; n < 4; ++n) {
    const int go = ob + wc*64 + n*16 + frow;
    const int h = go >> 6, d = go & 63;
#pragma unroll
    for (int m = 0; m < 4; ++m) {
      const int gm0 = m0 + wr*64 + m*16 + ((lane >> 4) << 2);
      const int b = gm0 >> 10, nn0 = gm0 & 1023;
      ushort4 o4;
      o4.x = f2b(acc[m][n][0]); o4.y = f2b(acc[m][n][1]);
      o4.z = f2b(acc[m][n][2]); o4.w = f2b(acc[m][n][3]);
      *(ushort4*)(vt + (((size_t)((b*12 + h)*64 + d)) << 10) + nn0) = o4;
    }
  }
}

// ---------------------------------------------------------------- attention
// r6-proven: 8 waves x 32 q-rows = QBLK 256; grid (bh=192, qt=4) XCD-grouped;
// K/V 2-buffer drain-0 pipeline; swapped-QK 32x32; defer-max (T13); T12 pack.
__global__ __launch_bounds__(512) void attn_fwd(
    const u16* __restrict__ q, const u16* __restrict__ kk,
    const u16* __restrict__ vt, u16* __restrict__ ao)
{
  __shared__ u16 lK[2][64*64];
  __shared__ u16 lV[2][64*64];
  const int tid = threadIdx.x, lane = tid & 63, wv = tid >> 6;
  const int l31 = lane & 31, hh = lane >> 5;
  const int bh = blockIdx.x, qt = blockIdx.y;
  const u16*  qb = q  + ((size_t)bh << 16);
  const char* kg = (const char*)(kk + ((size_t)bh << 16));
  const char* vg = (const char*)(vt + ((size_t)bh << 16));
  const int qrow = (qt << 8) + (wv << 5) + l31;
  bf16x8 qreg[4];
#pragma unroll
  for (int c = 0; c < 4; ++c)
    qreg[c] = *(const bf16x8*)((const char*)qb + (size_t)qrow*128 + c*32 + hh*16);
  f32x16 ot[2] = {};
  float mrun = -1e30f, lrun = 0.f;
  const int o1 = tid << 4;
  const int ko1 = o1 ^ (((o1 >> 7) & 7) << 4);
  const int d1 = o1 >> 7;
  const int vo1 = d1*2048 + ((o1 & 127) ^ ((d1 & 7) << 4));
  char* sK = (char*)lK;
  char* sV = (char*)lV;

#define ATTN_STAGE(buf, t) do { const int bo_ = (buf) << 13; \
    gld16(kg + ((t) << 13) + ko1, sK + bo_ + o1); \
    gld16(vg + ((t) << 7) + vo1, sV + bo_ + o1); } while (0)

  ATTN_STAGE(0, 0);
  asm volatile("s_waitcnt vmcnt(0) lgkmcnt(0)" ::: "memory");
  __builtin_amdgcn_s_barrier();
  for (int t0 = 0; t0 < 16; ++t0) {
    const int cur = t0 & 1;
    if (t0 < 15) ATTN_STAGE(cur ^ 1, t0 + 1);
    const char* bK = (const char*)lK + (cur << 13);
    const char* bV = (const char*)lV + (cur << 13);
    f32x16 s[2] = {};
#pragma unroll
    for (int tt = 0; tt < 2; ++tt) {
      const int row = (tt << 5) + l31;
      const int rb = row << 7;
      const int sw = (row & 7) << 4;
#pragma unroll
      for (int c = 0; c < 4; ++c) {
        bf16x8 kf = *(const bf16x8*)(bK + rb + (((c << 5) + (hh << 4)) ^ sw));
        s[tt] = MFMA32(kf, qreg[c], s[tt]);
      }
    }
    float mloc = s[0][0];
#pragma unroll
    for (int tt = 0; tt < 2; ++tt)
#pragma unroll
      for (int r = 0; r < 16; ++r) mloc = fmaxf(mloc, s[tt][r]);
    if (!__all(mloc <= mrun + 8.f)) {      // defer-max (T13)
      mloc = fmaxf(mloc, __shfl_xor(mloc, 32));
      const float mnew  = fmaxf(mrun, mloc);
      const float alpha = __builtin_amdgcn_exp2f(mrun - mnew);
      lrun *= alpha;
#pragma unroll
      for (int dt = 0; dt < 2; ++dt)
#pragma unroll
        for (int r = 0; r < 16; ++r) ot[dt][r] *= alpha;
      mrun = mnew;
    }
    float sum = 0.f;
#pragma unroll
    for (int tt = 0; tt < 2; ++tt)
#pragma unroll
      for (int r = 0; r < 16; ++r) {
        s[tt][r] = __builtin_amdgcn_exp2f(s[tt][r] - mrun);
        sum += s[tt][r];
      }
    sum += __shfl_xor(sum, 32);
    lrun += sum;
    bf16x8 pb[4];
#pragma unroll
    for (int tt = 0; tt < 2; ++tt) {
      u32 x0 = cvtpk(s[tt][0],  s[tt][1]);
      u32 y0 = cvtpk(s[tt][4],  s[tt][5]);
      u32 x1 = cvtpk(s[tt][2],  s[tt][3]);
      u32 y1 = cvtpk(s[tt][6],  s[tt][7]);
      asm("v_permlane32_swap_b32 %0, %1" : "+v"(x0), "+v"(y0));
      asm("v_permlane32_swap_b32 %0, %1" : "+v"(x1), "+v"(y1));
      u32 x2 = cvtpk(s[tt][8],  s[tt][9]);
      u32 y2 = cvtpk(s[tt][12], s[tt][13]);
      u32 x3 = cvtpk(s[tt][10], s[tt][11]);
      u32 y3 = cvtpk(s[tt][14], s[tt][15]);
      asm("v_permlane32_swap_b32 %0, %1" : "+v"(x2), "+v"(y2));
      asm("v_permlane32_swap_b32 %0, %1" : "+v"(x3), "+v"(y3));
      union { u32 u[4]; bf16x8 v; } a, b;
      a.u[0] = x0; a.u[1] = x1; a.u[2] = y0; a.u[3] = y1;
      b.u[0] = x2; b.u[1] = x3; b.u[2] = y2; b.u[3] = y3;
      pb[2*tt]     = a.v;
      pb[2*tt + 1] = b.v;
    }
#pragma unroll
    for (int dt = 0; dt < 2; ++dt) {
      const int row = (dt << 5) + l31;
      const int rb = row << 7;
      const int sw = (row & 7) << 4;
#pragma unroll
      for (int cc = 0; cc < 4; ++cc) {
        bf16x8 vf = *(const bf16x8*)(bV + rb + (((cc << 5) + (hh << 4)) ^ sw));
        ot[dt] = MFMA32(vf, pb[cc], ot[dt]);
      }
    }
    asm volatile("s_waitcnt vmcnt(0) lgkmcnt(0)" ::: "memory");
    __builtin_amdgcn_s_barrier();
  }
  const float linv = 1.f / lrun;
  const int b = bh / 12, h = bh - b * 12;
  u16* po = ao + ((size_t)(b*1024 + qrow)) * 768 + h*64;
#pragma unroll
  for (int dt = 0; dt < 2; ++dt) {
#pragma unroll
    for (int g = 0; g < 4; ++g) {
      ushort4 o4;
      o4.x = f2b(ot[dt][4*g + 0] * linv);
      o4.y = f2b(ot[dt][4*g + 1] * linv);
      o4.z = f2b(ot[dt][4*g + 2] * linv);
      o4.w = f2b(ot[dt][4*g + 3] * linv);
      *(ushort4*)(po + dt*32 + g*8 + hh*4) = o4;
    }
  }
}

// ---------------------------------------------------------------- proj GEMM
// r6-proven: 128x128 tile, 2-buffer drain-0 pipeline.
__global__ __launch_bounds__(256) void gemm_proj(
    const u16* __restrict__ ab, const u16* __restrict__ wb,
    const float* __restrict__ bias, float* __restrict__ out)
{
  __shared__ u16 lAp[2][128*32];
  __shared__ u16 lBp[2][128*32];
  const int tid = threadIdx.x;
  const int lane = tid & 63;
  const int wv = tid >> 6;
  const int wr = wv >> 1, wc = wv & 1;
  const int m0 = blockIdx.x << 7;
  const int o0 = blockIdx.y << 7;
  f32x4 acc[4][4] = {};
  const int srow = tid >> 2;
  const int sb   = (((tid & 3) ^ ((srow >> 1) & 3)) << 4);
  const char* gA0 = (const char*)(ab + (size_t)(m0 + srow)      * 768) + sb;
  const char* gA1 = (const char*)(ab + (size_t)(m0 + 64 + srow) * 768) + sb;
  const char* gB0 = (const char*)(wb + (size_t)(o0 + srow)      * 768) + sb;
  const char* gB1 = (const char*)(wb + (size_t)(o0 + 64 + srow) * 768) + sb;
  char* sAp = (char*)lAp + tid * 16;
  char* sBp = (char*)lBp + tid * 16;
  const int frow = lane & 15;
  const int fk   = (((lane >> 4) ^ ((frow >> 1) & 3)) << 4);

#define PSTG(buf, kt) do { const int kb_ = (kt) << 6; const int bo_ = (buf) << 13; \
    gld16(gA0 + kb_, sAp + bo_); gld16(gA1 + kb_, sAp + bo_ + 4096); \
    gld16(gB0 + kb_, sBp + bo_); gld16(gB1 + kb_, sBp + bo_ + 4096); } while (0)

  PSTG(0, 0);
  asm volatile("s_waitcnt vmcnt(0) lgkmcnt(0)" ::: "memory");
  __builtin_amdgcn_s_barrier();
  for (int kt = 0; kt < 24; ++kt) {
    const int cur = kt & 1;
    if (kt < 23) PSTG(cur ^ 1, kt + 1);
    const char* bA = (const char*)lAp + (cur << 13);
    const char* bB = (const char*)lBp + (cur << 13);
    bf16x8 af[4], bfr[4];
#pragma unroll
    for (int m = 0; m < 4; ++m)
      af[m] = *(const bf16x8*)(bA + ((wr*64 + m*16 + frow) << 6) + fk);
#pragma unroll
    for (int n = 0; n < 4; ++n)
      bfr[n] = *(const bf16x8*)(bB + ((wc*64 + n*16 + frow) << 6) + fk);
#pragma unroll
    for (int m = 0; m < 4; ++m)
#pragma unroll
      for (int n = 0; n < 4; ++n)
        acc[m][n] = MFMA16(af[m], bfr[n], acc[m][n]);
    asm volatile("s_waitcnt vmcnt(0) lgkmcnt(0)" ::: "memory");
    __builtin_amdgcn_s_barrier();
  }
#pragma unroll
  for (int n = 0; n < 4; ++n) {
    const int go = o0 + wc*64 + n*16 + (lane & 15);
    const float bv = bias[go];
#pragma unroll
    for (int m = 0; m < 4; ++m) {
#pragma unroll
      for (int r = 0; r < 4; ++r) {
        const int gm = m0 + wr*64 + m*16 + ((lane >> 4) << 2) + r;
        out[(size_t)gm * 768 + go] = acc[m][n][r] + bv;
      }
    }
  }
}

// ---------------------------------------------------------------- launch
extern "C" void kernel_launch(void* const* d_in, const int* in_sizes, int n_in,
                              void* d_out, int out_size, void* d_ws, size_t ws_size,
                              hipStream_t stream)
{
  (void)in_sizes; (void)n_in; (void)out_size; (void)ws_size;
  const float* x  = (const float*)d_in[0];
  const float* wq = (const float*)d_in[1];
  const float* wp = (const float*)d_in[2];
  const float* bp = (const float*)d_in[3];
  float* out = (float*)d_out;
  char* ws = (char*)d_ws;
  u16* xb     = (u16*)(ws);              // 25,165,824  x bf16 [16384][768]
  u16* wqkvb  = (u16*)(ws + 25165824);   //  3,538,944  w_qkv bf16
  u16* wprojb = (u16*)(ws + 28704768);   //  1,179,648  w_proj bf16
  u16* qa     = (u16*)(ws + 29884416);   // 25,165,824  q  [192][1024][64] (pre-scaled)
  u16* ka     = (u16*)(ws + 55050240);   // 25,165,824  k  [192][1024][64]
  u16* vta    = (u16*)(ws + 80216064);   // 25,165,824  v^T[192][64][1024]
  u16* ao     = xb;                      // alias: xb dead after gemm_qk/gemm_v

  cvt_bf16<<<2048, 256, 0, stream>>>((const float4*)x,  (ushort4*)xb,     3145728);
  cvt_bf16<<<1024, 256, 0, stream>>>((const float4*)wq, (ushort4*)wqkvb,   442368);
  cvt_bf16<<< 576, 256, 0, stream>>>((const float4*)wp, (ushort4*)wprojb,  147456);
  gemm_qk<<<dim3(128, 12), 256, 0, stream>>>(xb, wqkvb, qa, ka);
  gemm_v <<<dim3(128,  6), 256, 0, stream>>>(xb, wqkvb, vta);   // FIX: 6 y-blocks (was 3 -> half of V never written)
  attn_fwd<<<dim3(192, 4), 512, 0, stream>>>(qa, ka, vta, ao);
  gemm_proj<<<dim3(128, 6), 256, 0, stream>>>(ao, wprojb, bp, out);
}

// Round 12
// 204.273 us; speedup vs baseline: 1.2026x; 1.0127x over previous
//
#include <hip/hip_runtime.h>
#include <hip/hip_bf16.h>
#include <stdint.h>

typedef unsigned short u16;
typedef unsigned int   u32;
typedef short bf16x8 __attribute__((ext_vector_type(8)));
typedef float f32x4  __attribute__((ext_vector_type(4)));
typedef float f32x16 __attribute__((ext_vector_type(16)));

#define MFMA16(A,B,C) __builtin_amdgcn_mfma_f32_16x16x32_bf16((A),(B),(C),0,0,0)
#define MFMA32(A,B,C) __builtin_amdgcn_mfma_f32_32x32x16_bf16((A),(B),(C),0,0,0)

// fp32 -> bf16 round-to-nearest-even
__device__ __forceinline__ u16 f2b(float x) {
  u32 u = __float_as_uint(x);
  u += 0x7fffu + ((u >> 16) & 1u);
  return (u16)(u >> 16);
}
__device__ __forceinline__ u32 cvtpk(float lo, float hi) {
  u32 r;
  asm("v_cvt_pk_bf16_f32 %0, %1, %2" : "=v"(r) : "v"(lo), "v"(hi));
  return r;
}

typedef __attribute__((address_space(1))) const void glob_void;
typedef __attribute__((address_space(3))) void lds_void;
__device__ __forceinline__ void gld16(const void* g, void* s) {
  __builtin_amdgcn_global_load_lds((glob_void*)g, (lds_void*)s, 16, 0, 0);
}

// ---------------------------------------------------------------- convert
// Fused: x (3145728 float4) + w_qkv (442368) + w_proj (147456) -> one
// contiguous bf16 region (xb | wqkvb | wprojb in ws).
__global__ void cvt_all(const float4* __restrict__ x, const float4* __restrict__ wq,
                        const float4* __restrict__ wp, ushort4* __restrict__ out) {
  int stride = gridDim.x * blockDim.x;
  for (int i = blockIdx.x * blockDim.x + threadIdx.x; i < 3735552; i += stride) {
    float4 v = (i < 3145728) ? x[i] : (i < 3588096 ? wq[i - 3145728] : wp[i - 3588096]);
    ushort4 o;
    o.x = f2b(v.x); o.y = f2b(v.y); o.z = f2b(v.z); o.w = f2b(v.w);
    out[i] = o;
  }
}

// ---------------------------------------------------------------- Q/K GEMM
// r10-proven. 128x128 2-phase K-loop; MFMA operands SWAPPED (D = W · X^T):
// each lane holds 4 consecutive d for one seq row -> 16 ushort4 stores.
// by 0..5 -> q (pre-scaled by 0.125*log2e), 6..11 -> k.
__global__ __launch_bounds__(256) void gemm_qk(
    const u16* __restrict__ xb, const u16* __restrict__ wb,
    u16* __restrict__ q, u16* __restrict__ k)
{
  __shared__ u16 lA[2][128*32];
  __shared__ u16 lB[2][128*32];
  const int tid = threadIdx.x;
  const int lane = tid & 63;
  const int wv = tid >> 6;
  const int wr = wv >> 1, wc = wv & 1;
  const int m0 = blockIdx.x << 7;
  const int by = blockIdx.y;
  const int isq = by < 6;
  const int o0 = by << 7;                       // col in [0,1536)
  f32x4 acc[4][4] = {};
  const int srow = tid >> 2;
  const int sb   = (((tid & 3) ^ ((srow >> 1) & 3)) << 4);
  const char* gA0 = (const char*)(xb + (size_t)(m0 + srow)      * 768) + sb;
  const char* gA1 = (const char*)(xb + (size_t)(m0 + 64 + srow) * 768) + sb;
  const char* gB0 = (const char*)(wb + (size_t)(o0 + srow)      * 768) + sb;
  const char* gB1 = (const char*)(wb + (size_t)(o0 + 64 + srow) * 768) + sb;
  char* sA = (char*)lA + tid * 16;
  char* sB = (char*)lB + tid * 16;
  const int frow = lane & 15;
  const int fk   = (((lane >> 4) ^ ((frow >> 1) & 3)) << 4);

#define KSTG(buf, kt) do { const int kb_ = (kt) << 6; const int bo_ = (buf) << 13; \
    gld16(gA0 + kb_, sA + bo_); gld16(gA1 + kb_, sA + bo_ + 4096); \
    gld16(gB0 + kb_, sB + bo_); gld16(gB1 + kb_, sB + bo_ + 4096); } while (0)

  KSTG(0, 0);
  asm volatile("s_waitcnt vmcnt(0) lgkmcnt(0)" ::: "memory");
  __builtin_amdgcn_s_barrier();
  for (int kt = 0; kt < 24; ++kt) {
    const int cur = kt & 1;
    if (kt < 23) KSTG(cur ^ 1, kt + 1);
    const char* bA = (const char*)lA + (cur << 13);
    const char* bB = (const char*)lB + (cur << 13);
    bf16x8 af[4], bfr[4];
#pragma unroll
    for (int m = 0; m < 4; ++m)
      af[m] = *(const bf16x8*)(bA + ((wr*64 + m*16 + frow) << 6) + fk);
#pragma unroll
    for (int n = 0; n < 4; ++n)
      bfr[n] = *(const bf16x8*)(bB + ((wc*64 + n*16 + frow) << 6) + fk);
#pragma unroll
    for (int m = 0; m < 4; ++m)
#pragma unroll
      for (int n = 0; n < 4; ++n)
        acc[m][n] = MFMA16(bfr[n], af[m], acc[m][n]);   // SWAPPED
    asm volatile("s_waitcnt vmcnt(0) lgkmcnt(0)" ::: "memory");
    __builtin_amdgcn_s_barrier();
  }
  const int ob = (by - (isq ? 0 : 6)) << 7;      // col within q or k [0,768)
  const float scale = isq ? 0.18033688011112042f : 1.0f;
  u16* dst = isq ? q : k;
  const int hh4 = (lane >> 4) << 2;
#pragma unroll
  for (int n = 0; n < 4; ++n) {
    const int go = ob + wc*64 + n*16 + hh4;      // o (head*64+d), d0 mult of 4
    const int h = go >> 6, d0 = go & 63;
#pragma unroll
    for (int m = 0; m < 4; ++m) {
      const int gm = m0 + wr*64 + m*16 + frow;   // seq index (col=lane&15)
      const int b = gm >> 10, nn = gm & 1023;
      ushort4 o4;
      o4.x = f2b(acc[m][n][0] * scale);
      o4.y = f2b(acc[m][n][1] * scale);
      o4.z = f2b(acc[m][n][2] * scale);
      o4.w = f2b(acc[m][n][3] * scale);
      *(ushort4*)(dst + (((size_t)((b*12 + h)*1024 + nn)) << 6) + d0) = o4;
    }
  }
}

// ---------------------------------------------------------------- V GEMM
// r10-proven. Normal operand order: r varies nn -> ushort4 into vt[d][nn].
__global__ __launch_bounds__(256) void gemm_v(
    const u16* __restrict__ xb, const u16* __restrict__ wb,
    u16* __restrict__ vt)
{
  __shared__ u16 lA[2][128*32];
  __shared__ u16 lB[2][128*32];
  const int tid = threadIdx.x;
  const int lane = tid & 63;
  const int wv = tid >> 6;
  const int wr = wv >> 1, wc = wv & 1;
  const int m0 = blockIdx.x << 7;
  const int by = blockIdx.y;
  const int o0 = 1536 + (by << 7);
  f32x4 acc[4][4] = {};
  const int srow = tid >> 2;
  const int sb   = (((tid & 3) ^ ((srow >> 1) & 3)) << 4);
  const char* gA0 = (const char*)(xb + (size_t)(m0 + srow)      * 768) + sb;
  const char* gA1 = (const char*)(xb + (size_t)(m0 + 64 + srow) * 768) + sb;
  const char* gB0 = (const char*)(wb + (size_t)(o0 + srow)      * 768) + sb;
  const char* gB1 = (const char*)(wb + (size_t)(o0 + 64 + srow) * 768) + sb;
  char* sA = (char*)lA + tid * 16;
  char* sB = (char*)lB + tid * 16;
  const int frow = lane & 15;
  const int fk   = (((lane >> 4) ^ ((frow >> 1) & 3)) << 4);

#define VSTG(buf, kt) do { const int kb_ = (kt) << 6; const int bo_ = (buf) << 13; \
    gld16(gA0 + kb_, sA + bo_); gld16(gA1 + kb_, sA + bo_ + 4096); \
    gld16(gB0 + kb_, sB + bo_); gld16(gB1 + kb_, sB + bo_ + 4096); } while (0)

  VSTG(0, 0);
  asm volatile("s_waitcnt vmcnt(0) lgkmcnt(0)" ::: "memory");
  __builtin_amdgcn_s_barrier();
  for (int kt = 0; kt < 24; ++kt) {
    const int cur = kt & 1;
    if (kt < 23) VSTG(cur ^ 1, kt + 1);
    const char* bA = (const char*)lA + (cur << 13);
    const char* bB = (const char*)lB + (cur << 13);
    bf16x8 af[4], bfr[4];
#pragma unroll
    for (int m = 0; m < 4; ++m)
      af[m] = *(const bf16x8*)(bA + ((wr*64 + m*16 + frow) << 6) + fk);
#pragma unroll
    for (int n = 0; n < 4; ++n)
      bfr[n] = *(const bf16x8*)(bB + ((wc*64 + n*16 + frow) << 6) + fk);
#pragma unroll
    for (int m = 0; m < 4; ++m)
#pragma unroll
      for (int n = 0; n < 4; ++n)
        acc[m][n] = MFMA16(af[m], bfr[n], acc[m][n]);
    asm volatile("s_waitcnt vmcnt(0) lgkmcnt(0)" ::: "memory");
    __builtin_amdgcn_s_barrier();
  }
  const int ob = by << 7;                        // col within v [0,768)
#pragma unroll
  for (int n = 0; n < 4; ++n) {
    const int go = ob + wc*64 + n*16 + frow;
    const int h = go >> 6, d = go & 63;
#pragma unroll
    for (int m = 0; m < 4; ++m) {
      const int gm0 = m0 + wr*64 + m*16 + ((lane >> 4) << 2);
      const int b = gm0 >> 10, nn0 = gm0 & 1023;
      ushort4 o4;
      o4.x = f2b(acc[m][n][0]); o4.y = f2b(acc[m][n][1]);
      o4.z = f2b(acc[m][n][2]); o4.w = f2b(acc[m][n][3]);
      *(ushort4*)(vt + (((size_t)((b*12 + h)*64 + d)) << 10) + nn0) = o4;
    }
  }
}

// ---------------------------------------------------------------- attention
// r10-proven (revert of the raced T15 pipeline): 8 waves x 32 q-rows = QBLK
// 256; grid (bh=192, qt=4) XCD-grouped; K/V 2-buffer drain-0 pipeline;
// swapped-QK 32x32; defer-max (T13); cvt_pk+permlane (T12).
__global__ __launch_bounds__(512) void attn_fwd(
    const u16* __restrict__ q, const u16* __restrict__ kk,
    const u16* __restrict__ vt, u16* __restrict__ ao)
{
  __shared__ u16 lK[2][64*64];
  __shared__ u16 lV[2][64*64];
  const int tid = threadIdx.x, lane = tid & 63, wv = tid >> 6;
  const int l31 = lane & 31, hh = lane >> 5;
  const int bh = blockIdx.x, qt = blockIdx.y;
  const u16*  qb = q  + ((size_t)bh << 16);
  const char* kg = (const char*)(kk + ((size_t)bh << 16));
  const char* vg = (const char*)(vt + ((size_t)bh << 16));
  const int qrow = (qt << 8) + (wv << 5) + l31;
  bf16x8 qreg[4];
#pragma unroll
  for (int c = 0; c < 4; ++c)
    qreg[c] = *(const bf16x8*)((const char*)qb + (size_t)qrow*128 + c*32 + hh*16);
  f32x16 ot[2] = {};
  float mrun = -1e30f, lrun = 0.f;
  const int o1 = tid << 4;
  const int ko1 = o1 ^ (((o1 >> 7) & 7) << 4);
  const int d1 = o1 >> 7;
  const int vo1 = d1*2048 + ((o1 & 127) ^ ((d1 & 7) << 4));
  char* sK = (char*)lK;
  char* sV = (char*)lV;

#define ATTN_STAGE(buf, t) do { const int bo_ = (buf) << 13; \
    gld16(kg + ((t) << 13) + ko1, sK + bo_ + o1); \
    gld16(vg + ((t) << 7) + vo1, sV + bo_ + o1); } while (0)

  ATTN_STAGE(0, 0);
  asm volatile("s_waitcnt vmcnt(0) lgkmcnt(0)" ::: "memory");
  __builtin_amdgcn_s_barrier();
  for (int t0 = 0; t0 < 16; ++t0) {
    const int cur = t0 & 1;
    if (t0 < 15) ATTN_STAGE(cur ^ 1, t0 + 1);
    const char* bK = (const char*)lK + (cur << 13);
    const char* bV = (const char*)lV + (cur << 13);
    f32x16 s[2] = {};
#pragma unroll
    for (int tt = 0; tt < 2; ++tt) {
      const int row = (tt << 5) + l31;
      const int rb = row << 7;
      const int sw = (row & 7) << 4;
#pragma unroll
      for (int c = 0; c < 4; ++c) {
        bf16x8 kf = *(const bf16x8*)(bK + rb + (((c << 5) + (hh << 4)) ^ sw));
        s[tt] = MFMA32(kf, qreg[c], s[tt]);
      }
    }
    float mloc = s[0][0];
#pragma unroll
    for (int tt = 0; tt < 2; ++tt)
#pragma unroll
      for (int r = 0; r < 16; ++r) mloc = fmaxf(mloc, s[tt][r]);
    if (!__all(mloc <= mrun + 8.f)) {      // defer-max (T13)
      mloc = fmaxf(mloc, __shfl_xor(mloc, 32));
      const float mnew  = fmaxf(mrun, mloc);
      const float alpha = __builtin_amdgcn_exp2f(mrun - mnew);
      lrun *= alpha;
#pragma unroll
      for (int dt = 0; dt < 2; ++dt)
#pragma unroll
        for (int r = 0; r < 16; ++r) ot[dt][r] *= alpha;
      mrun = mnew;
    }
    float sum = 0.f;
#pragma unroll
    for (int tt = 0; tt < 2; ++tt)
#pragma unroll
      for (int r = 0; r < 16; ++r) {
        s[tt][r] = __builtin_amdgcn_exp2f(s[tt][r] - mrun);
        sum += s[tt][r];
      }
    sum += __shfl_xor(sum, 32);
    lrun += sum;
    bf16x8 pb[4];
#pragma unroll
    for (int tt = 0; tt < 2; ++tt) {
      u32 x0 = cvtpk(s[tt][0],  s[tt][1]);
      u32 y0 = cvtpk(s[tt][4],  s[tt][5]);
      u32 x1 = cvtpk(s[tt][2],  s[tt][3]);
      u32 y1 = cvtpk(s[tt][6],  s[tt][7]);
      asm("v_permlane32_swap_b32 %0, %1" : "+v"(x0), "+v"(y0));
      asm("v_permlane32_swap_b32 %0, %1" : "+v"(x1), "+v"(y1));
      u32 x2 = cvtpk(s[tt][8],  s[tt][9]);
      u32 y2 = cvtpk(s[tt][12], s[tt][13]);
      u32 x3 = cvtpk(s[tt][10], s[tt][11]);
      u32 y3 = cvtpk(s[tt][14], s[tt][15]);
      asm("v_permlane32_swap_b32 %0, %1" : "+v"(x2), "+v"(y2));
      asm("v_permlane32_swap_b32 %0, %1" : "+v"(x3), "+v"(y3));
      union { u32 u[4]; bf16x8 v; } a, b;
      a.u[0] = x0; a.u[1] = x1; a.u[2] = y0; a.u[3] = y1;
      b.u[0] = x2; b.u[1] = x3; b.u[2] = y2; b.u[3] = y3;
      pb[2*tt]     = a.v;
      pb[2*tt + 1] = b.v;
    }
#pragma unroll
    for (int dt = 0; dt < 2; ++dt) {
      const int row = (dt << 5) + l31;
      const int rb = row << 7;
      const int sw = (row & 7) << 4;
#pragma unroll
      for (int cc = 0; cc < 4; ++cc) {
        bf16x8 vf = *(const bf16x8*)(bV + rb + (((cc << 5) + (hh << 4)) ^ sw));
        ot[dt] = MFMA32(vf, pb[cc], ot[dt]);
      }
    }
    asm volatile("s_waitcnt vmcnt(0) lgkmcnt(0)" ::: "memory");
    __builtin_amdgcn_s_barrier();
  }
  const float linv = 1.f / lrun;
  const int b = bh / 12, h = bh - b * 12;
  u16* po = ao + ((size_t)(b*1024 + qrow)) * 768 + h*64;
#pragma unroll
  for (int dt = 0; dt < 2; ++dt) {
#pragma unroll
    for (int g = 0; g < 4; ++g) {
      ushort4 o4;
      o4.x = f2b(ot[dt][4*g + 0] * linv);
      o4.y = f2b(ot[dt][4*g + 1] * linv);
      o4.z = f2b(ot[dt][4*g + 2] * linv);
      o4.w = f2b(ot[dt][4*g + 3] * linv);
      *(ushort4*)(po + dt*32 + g*8 + hh*4) = o4;
    }
  }
}

// ---------------------------------------------------------------- proj GEMM
// 128x128 2-phase K-loop; SWAPPED operands (r10-validated pattern from
// gemm_qk): lane holds 4 consecutive out-cols -> float4 stores + float4 bias.
__global__ __launch_bounds__(256) void gemm_proj(
    const u16* __restrict__ ab, const u16* __restrict__ wb,
    const float* __restrict__ bias, float* __restrict__ out)
{
  __shared__ u16 lAp[2][128*32];
  __shared__ u16 lBp[2][128*32];
  const int tid = threadIdx.x;
  const int lane = tid & 63;
  const int wv = tid >> 6;
  const int wr = wv >> 1, wc = wv & 1;
  const int m0 = blockIdx.x << 7;
  const int o0 = blockIdx.y << 7;
  f32x4 acc[4][4] = {};
  const int srow = tid >> 2;
  const int sb   = (((tid & 3) ^ ((srow >> 1) & 3)) << 4);
  const char* gA0 = (const char*)(ab + (size_t)(m0 + srow)      * 768) + sb;
  const char* gA1 = (const char*)(ab + (size_t)(m0 + 64 + srow) * 768) + sb;
  const char* gB0 = (const char*)(wb + (size_t)(o0 + srow)      * 768) + sb;
  const char* gB1 = (const char*)(wb + (size_t)(o0 + 64 + srow) * 768) + sb;
  char* sAp = (char*)lAp + tid * 16;
  char* sBp = (char*)lBp + tid * 16;
  const int frow = lane & 15;
  const int fk   = (((lane >> 4) ^ ((frow >> 1) & 3)) << 4);

#define PSTG(buf, kt) do { const int kb_ = (kt) << 6; const int bo_ = (buf) << 13; \
    gld16(gA0 + kb_, sAp + bo_); gld16(gA1 + kb_, sAp + bo_ + 4096); \
    gld16(gB0 + kb_, sBp + bo_); gld16(gB1 + kb_, sBp + bo_ + 4096); } while (0)

  PSTG(0, 0);
  asm volatile("s_waitcnt vmcnt(0) lgkmcnt(0)" ::: "memory");
  __builtin_amdgcn_s_barrier();
  for (int kt = 0; kt < 24; ++kt) {
    const int cur = kt & 1;
    if (kt < 23) PSTG(cur ^ 1, kt + 1);
    const char* bA = (const char*)lAp + (cur << 13);
    const char* bB = (const char*)lBp + (cur << 13);
    bf16x8 af[4], bfr[4];
#pragma unroll
    for (int m = 0; m < 4; ++m)
      af[m] = *(const bf16x8*)(bA + ((wr*64 + m*16 + frow) << 6) + fk);
#pragma unroll
    for (int n = 0; n < 4; ++n)
      bfr[n] = *(const bf16x8*)(bB + ((wc*64 + n*16 + frow) << 6) + fk);
#pragma unroll
    for (int m = 0; m < 4; ++m)
#pragma unroll
      for (int n = 0; n < 4; ++n)
        acc[m][n] = MFMA16(bfr[n], af[m], acc[m][n]);   // SWAPPED
    asm volatile("s_waitcnt vmcnt(0) lgkmcnt(0)" ::: "memory");
    __builtin_amdgcn_s_barrier();
  }
  const int hh4 = (lane >> 4) << 2;
#pragma unroll
  for (int n = 0; n < 4; ++n) {
    const int go0 = o0 + wc*64 + n*16 + hh4;     // 4 consecutive out cols
    const float4 bv = *(const float4*)(bias + go0);
#pragma unroll
    for (int m = 0; m < 4; ++m) {
      const int gm = m0 + wr*64 + m*16 + frow;   // row (col=lane&15)
      float4 o4;
      o4.x = acc[m][n][0] + bv.x;
      o4.y = acc[m][n][1] + bv.y;
      o4.z = acc[m][n][2] + bv.z;
      o4.w = acc[m][n][3] + bv.w;
      *(float4*)(out + (size_t)gm * 768 + go0) = o4;
    }
  }
}

// ---------------------------------------------------------------- launch
extern "C" void kernel_launch(void* const* d_in, const int* in_sizes, int n_in,
                              void* d_out, int out_size, void* d_ws, size_t ws_size,
                              hipStream_t stream)
{
  (void)in_sizes; (void)n_in; (void)out_size; (void)ws_size;
  const float* x  = (const float*)d_in[0];
  const float* wq = (const float*)d_in[1];
  const float* wp = (const float*)d_in[2];
  const float* bp = (const float*)d_in[3];
  float* out = (float*)d_out;
  char* ws = (char*)d_ws;
  u16* xb     = (u16*)(ws);              // 25,165,824  x bf16 [16384][768]
  u16* wqkvb  = (u16*)(ws + 25165824);   //  3,538,944  w_qkv bf16
  u16* wprojb = (u16*)(ws + 28704768);   //  1,179,648  w_proj bf16
  u16* qa     = (u16*)(ws + 29884416);   // 25,165,824  q  [192][1024][64] (pre-scaled)
  u16* ka     = (u16*)(ws + 55050240);   // 25,165,824  k  [192][1024][64]
  u16* vta    = (u16*)(ws + 80216064);   // 25,165,824  v^T[192][64][1024]
  u16* ao     = xb;                      // alias: xb dead after gemm_qk/gemm_v

  cvt_all<<<2048, 256, 0, stream>>>((const float4*)x, (const float4*)wq,
                                    (const float4*)wp, (ushort4*)ws);
  gemm_qk<<<dim3(128, 12), 256, 0, stream>>>(xb, wqkvb, qa, ka);
  gemm_v <<<dim3(128,  6), 256, 0, stream>>>(xb, wqkvb, vta);
  attn_fwd<<<dim3(192, 4), 512, 0, stream>>>(qa, ka, vta, ao);
  gemm_proj<<<dim3(128, 6), 256, 0, stream>>>(ao, wprojb, bp, out);
}